// Round 19
// baseline (172.192 us; speedup 1.0000x reference)
//
#include <hip/hip_runtime.h>

typedef __attribute__((ext_vector_type(8))) short s8v;   // 8 bf16 (4 VGPRs) MFMA A/B frag
typedef __attribute__((ext_vector_type(4))) float f4v;   // MFMA C/D frag

#define QSC (0.17677669529663687f * 1.4426950408889634f)  // 1/sqrt(32) * log2(e), folded into q

__device__ __forceinline__ unsigned short f2bf(float x) {
    unsigned u = __float_as_uint(x);
    return (unsigned short)((u + 0x7fffu + ((u >> 16) & 1u)) >> 16);  // RNE
}
__device__ __forceinline__ float bf2f(unsigned short h) {
    return __uint_as_float(((unsigned)h) << 16);
}
// truncation pack (round-toward-zero; P>=0 and O/L use the same truncated P)
__device__ __forceinline__ unsigned trunc2(float a, float b) {
    return (__float_as_uint(b) & 0xffff0000u) | (__float_as_uint(a) >> 16);
}

// One-shot weight prep (+ wpe transpose to [9][256])
__global__ __launch_bounds__(256) void wconv_kernel(
    const float* __restrict__ wqk, const float* __restrict__ sqk, const float* __restrict__ bqk,
    const float* __restrict__ wv,  const float* __restrict__ sv,  const float* __restrict__ bv,
    const float* __restrict__ wprj, const float* __restrict__ sprj,
    const float* __restrict__ wm1, const float* __restrict__ sm1, const float* __restrict__ bm1,
    const float* __restrict__ wm2, const float* __restrict__ sm2,
    const float* __restrict__ wpe9,
    unsigned short* __restrict__ Wqkv, unsigned short* __restrict__ Wp,
    unsigned short* __restrict__ Wm1,  unsigned short* __restrict__ Wm2,
    float* __restrict__ bpad, float* __restrict__ bqv, float* __restrict__ wpeT)
{
    int i = blockIdx.x * 256 + threadIdx.x;
    if (i < 196608) {                       // Wqkv [768][256]
        int o = i >> 8, c = i & 255;
        float w;
        if (o < 512) { float f = ((o & 127) < 64) ? QSC : 1.f; w = wqk[i] * sqk[o] * f; }
        else          w = wv[(o - 512) * 256 + c] * sv[o - 512];
        Wqkv[i] = f2bf(w);
    } else if (i < 262144) {                // w_proj [256][256]
        int j = i - 196608; int o = j >> 8; Wp[j] = f2bf(wprj[j] * sprj[o]);
    } else if (i < 360448) {                // w_m1 [384pad][256]
        int j = i - 262144; int o = j >> 8, c = j & 255;
        Wm1[j] = (o < 307) ? f2bf(wm1[o * 256 + c] * sm1[o]) : (unsigned short)0;
    } else if (i < 458752) {                // w_m2 [256][384pad]
        int j = i - 360448; int o = j / 384, c = j - o * 384;
        Wm2[j] = (c < 307) ? f2bf(wm2[o * 307 + c] * sm2[o]) : (unsigned short)0;
    } else if (i < 459136) {                // b_m1 padded to 384
        int j = i - 458752; bpad[j] = (j < 307) ? bm1[j] : 0.f;
    } else if (i < 459904) {                // bqv[768]
        int j = i - 459136;
        bqv[j] = (j < 512) ? (bqk[j] * (((j & 127) < 64) ? QSC : 1.f)) : bv[j - 512];
    } else if (i < 462208) {                // wpeT [9][256]
        int j = i - 459904; int k = j >> 8, c = j & 255;
        wpeT[j] = wpe9[c * 9 + k];
    }
}

// Fused transpose + qkv GEMM (R16 form: LDS double-buffer, one barrier per kc,
// next-tile loads issued after the barrier to overlap MFMA; measured ~= R8).
__global__ __launch_bounds__(256) void mmqkv_kernel(
    const float* __restrict__ X, const unsigned short* __restrict__ Wb,
    const float* __restrict__ bi,
    unsigned short* __restrict__ qP, unsigned short* __restrict__ kP,
    unsigned short* __restrict__ vC, unsigned short* __restrict__ vT)
{
    __shared__ unsigned short Ap[2][64][40];
    __shared__ unsigned short Wt[2][128][40];
    const int tid = threadIdx.x, lane = tid & 63, wv = tid >> 6;
    const int lo4 = lane & 15, quad = lane >> 4;
    const int p0 = blockIdx.x * 64, o0 = blockIdx.y * 128, bB = blockIdx.z;
    const int ph = (wv & 1) * 32, oh = (wv >> 1) * 64;
    const int c2 = tid & 15, pg = tid >> 4;
    const int oW0 = tid >> 2, oW1 = (tid + 256) >> 2;
    const int cW = (tid & 3) * 8;
    const float* xb = X + (size_t)bB * 256 * 4096;

    f4v acc[4][2];
    #pragma unroll
    for (int i = 0; i < 4; i++)
        #pragma unroll
        for (int j = 0; j < 2; j++)
            acc[i][j] = (f4v){0.f, 0.f, 0.f, 0.f};

    // tile 0: load + stage into buf 0
    {
        float4 fa = *(const float4*)&xb[(size_t)(2 * c2) * 4096 + p0 + pg * 4];
        float4 fb = *(const float4*)&xb[(size_t)(2 * c2 + 1) * 4096 + p0 + pg * 4];
        uint4 wReg0 = *(const uint4*)(Wb + (size_t)(o0 + oW0) * 256 + cW);
        uint4 wReg1 = *(const uint4*)(Wb + (size_t)(o0 + oW1) * 256 + cW);
        float av[4] = {fa.x, fa.y, fa.z, fa.w};
        float bv2[4] = {fb.x, fb.y, fb.z, fb.w};
        #pragma unroll
        for (int i = 0; i < 4; i++)
            *(unsigned*)&Ap[0][pg * 4 + i][2 * c2] =
                (unsigned)f2bf(av[i]) | ((unsigned)f2bf(bv2[i]) << 16);
        *(uint4*)&Wt[0][oW0][cW] = wReg0;
        *(uint4*)&Wt[0][oW1][cW] = wReg1;
    }

    for (int kc = 0; kc < 8; kc++) {
        const int cur = kc & 1, nxt = cur ^ 1;
        __syncthreads();                      // buf[cur] staged for all waves
        float4 fa, fb;
        uint4 wReg0, wReg1;
        if (kc < 7) {                         // issue next-tile loads; overlap MFMA
            int k1 = (kc + 1) * 32;
            fa = *(const float4*)&xb[(size_t)(k1 + 2 * c2) * 4096 + p0 + pg * 4];
            fb = *(const float4*)&xb[(size_t)(k1 + 2 * c2 + 1) * 4096 + p0 + pg * 4];
            wReg0 = *(const uint4*)(Wb + (size_t)(o0 + oW0) * 256 + k1 + cW);
            wReg1 = *(const uint4*)(Wb + (size_t)(o0 + oW1) * 256 + k1 + cW);
        }
        s8v af[4], bx[2];
        #pragma unroll
        for (int of = 0; of < 4; of++)
            af[of] = *(const s8v*)&Wt[cur][oh + of * 16 + lo4][quad * 8];
        #pragma unroll
        for (int pf = 0; pf < 2; pf++)
            bx[pf] = *(const s8v*)&Ap[cur][ph + pf * 16 + lo4][quad * 8];
        #pragma unroll
        for (int of = 0; of < 4; of++)
            #pragma unroll
            for (int pf = 0; pf < 2; pf++)
                acc[of][pf] = __builtin_amdgcn_mfma_f32_16x16x32_bf16(af[of], bx[pf], acc[of][pf], 0, 0, 0);
        if (kc < 7) {                         // stage next tile into the other buffer
            float av[4] = {fa.x, fa.y, fa.z, fa.w};
            float bv2[4] = {fb.x, fb.y, fb.z, fb.w};
            #pragma unroll
            for (int i = 0; i < 4; i++)
                *(unsigned*)&Ap[nxt][pg * 4 + i][2 * c2] =
                    (unsigned)f2bf(av[i]) | ((unsigned)f2bf(bv2[i]) << 16);
            *(uint4*)&Wt[nxt][oW0][cW] = wReg0;
            *(uint4*)&Wt[nxt][oW1][cW] = wReg1;
        }
    }
    #pragma unroll
    for (int of = 0; of < 4; of++) {
        int ob = o0 + oh + of * 16 + quad * 4;
        float4 bb = *(const float4*)&bi[ob];
        float bbv[4] = {bb.x, bb.y, bb.z, bb.w};
        #pragma unroll
        for (int pf = 0; pf < 2; pf++) {
            int p = p0 + ph + pf * 16 + lo4;
            unsigned short b4[4];
            #pragma unroll
            for (int r = 0; r < 4; r++) b4[r] = f2bf(acc[of][pf][r] + bbv[r]);
            if (ob < 512) {              // wave-uniform branch (64-wide o-ranges)
                int gg = ob >> 7, rr = ob & 127;
                int hh = (rr & 63) >> 3, j0 = rr & 7;
                unsigned short* dst = (rr >= 64) ? kP : qP;
                *(ushort4*)&dst[((((size_t)(bB * 4 + gg)) * 8 + hh) * 1024 + (p & 1023)) * 32
                                + (p >> 10) * 8 + j0] = *(ushort4*)b4;
            } else {
                *(ushort4*)&vC[((size_t)(bB * 4096 + p)) * 256 + (ob - 512)] = *(ushort4*)b4;
                #pragma unroll
                for (int r = 0; r < 4; r++)
                    vT[((size_t)(bB * 256 + ob - 512 + r)) * 4096 + p] = b4[r];
            }
        }
    }
}

// MFMA area-attention (R8 form — best measured): barrier-free, packed Q/K,
// per-wave DOUBLE-BUFFERED P LDS (XOR-swizzled), spl=2, exp2f builtin.
__global__ __launch_bounds__(256) void attn_kernel(
    const unsigned short* __restrict__ qP, const unsigned short* __restrict__ kP,
    const unsigned short* __restrict__ vT,
    unsigned short* __restrict__ Opart, float* __restrict__ Lpart)
{
    __shared__ unsigned short Pq[4][2][32][64];   // [wave][buf][q][m], rows 128B, XOR-swizzled
    const int tid = threadIdx.x;
    const int w = tid >> 6, lane = tid & 63;
    const int lo4 = lane & 15, quad = lane >> 4;
    const int swz = (lo4 & 7) << 4;               // byte-XOR within 128B row
    const int n0 = blockIdx.z * 128;
    const int h = blockIdx.y;
    const int z = blockIdx.x;                     // 16 = ba(0..7)<<1 | spl
    const int ba = z >> 1, spl = z & 1;
    const int bB = ba >> 2, g = ba & 3;
    const int mbase = spl * 512;

    const unsigned short* qb = qP + (((size_t)(bB * 4) + g) * 8 + h) * 32768;
    const unsigned short* kb = kP + (((size_t)(bB * 4) + g) * 8 + h) * 32768;

    s8v qf[2];
    #pragma unroll
    for (int qc = 0; qc < 2; qc++)
        qf[qc] = *(const s8v*)(qb + (size_t)(n0 + w * 32 + qc * 16 + lo4) * 32 + quad * 8);
    const int dd0 = lo4, dd1 = 16 + lo4;
    const unsigned short* vb0 = vT + ((size_t)(bB * 256 + g * 64 + h * 8 + (dd0 & 7))) * 4096 + (dd0 >> 3) * 1024 + mbase + quad * 8;
    const unsigned short* vb1 = vT + ((size_t)(bB * 256 + g * 64 + h * 8 + (dd1 & 7))) * 4096 + (dd1 >> 3) * 1024 + mbase + quad * 8;

    f4v oacc[2][2], Lacc[2];
    #pragma unroll
    for (int i = 0; i < 2; i++) {
        Lacc[i] = (f4v){0.f, 0.f, 0.f, 0.f};
        #pragma unroll
        for (int j = 0; j < 2; j++)
            oacc[i][j] = (f4v){0.f, 0.f, 0.f, 0.f};
    }
    s8v ones;
    #pragma unroll
    for (int j = 0; j < 8; j++) ones[j] = (short)0x3F80;   // bf16 1.0

    s8v kf[4], vCur[2][2];
    #pragma unroll
    for (int mf = 0; mf < 4; mf++)
        kf[mf] = *(const s8v*)(kb + (size_t)(mbase + mf * 16 + lo4) * 32 + quad * 8);

    #pragma unroll
    for (int sc = 0; sc < 8; sc++) {
        // V for chunk sc (consumed by PV(sc) next iteration / epilogue)
        s8v vNew[2][2];
        #pragma unroll
        for (int mc = 0; mc < 2; mc++) {
            vNew[mc][0] = *(const s8v*)(vb0 + sc * 64 + mc * 32);
            vNew[mc][1] = *(const s8v*)(vb1 + sc * 64 + mc * 32);
        }
        // K for chunk sc+1
        s8v kfn[4];
        if (sc < 7) {
            #pragma unroll
            for (int mf = 0; mf < 4; mf++)
                kfn[mf] = *(const s8v*)(kb + (size_t)(mbase + (sc + 1) * 64 + mf * 16 + lo4) * 32 + quad * 8);
        }
        // QK(sc)
        f4v sT[4][2];
        __builtin_amdgcn_s_setprio(1);
        #pragma unroll
        for (int mf = 0; mf < 4; mf++)
            #pragma unroll
            for (int qc = 0; qc < 2; qc++)
                sT[mf][qc] = __builtin_amdgcn_mfma_f32_16x16x32_bf16(kf[mf], qf[qc], (f4v){0.f, 0.f, 0.f, 0.f}, 0, 0, 0);
        __builtin_amdgcn_s_setprio(0);
        // exp(sc) + write P(sc) into buf sc&1
        #pragma unroll
        for (int qc = 0; qc < 2; qc++) {
            char* prow = (char*)&Pq[w][sc & 1][qc * 16 + lo4][0];
            #pragma unroll
            for (int mf = 0; mf < 4; mf++) {
                float p0v = __builtin_amdgcn_exp2f(sT[mf][qc][0]);
                float p1v = __builtin_amdgcn_exp2f(sT[mf][qc][1]);
                float p2v = __builtin_amdgcn_exp2f(sT[mf][qc][2]);
                float p3v = __builtin_amdgcn_exp2f(sT[mf][qc][3]);
                uint2 pk;
                pk.x = trunc2(p0v, p1v);
                pk.y = trunc2(p2v, p3v);
                *(uint2*)(prow + ((mf * 32 + quad * 8) ^ swz)) = pk;
            }
        }
        // PV(sc-1) from the other buffer, V loaded last iteration
        if (sc > 0) {
            #pragma unroll
            for (int mc = 0; mc < 2; mc++) {
                s8v pfr[2];
                #pragma unroll
                for (int qc = 0; qc < 2; qc++)
                    pfr[qc] = *(const s8v*)((const char*)&Pq[w][(sc - 1) & 1][qc * 16 + lo4][0] + ((mc * 64 + quad * 16) ^ swz));
                __builtin_amdgcn_s_setprio(1);
                #pragma unroll
                for (int df = 0; df < 2; df++)
                    #pragma unroll
                    for (int qc = 0; qc < 2; qc++)
                        oacc[df][qc] = __builtin_amdgcn_mfma_f32_16x16x32_bf16(vCur[mc][df], pfr[qc], oacc[df][qc], 0, 0, 0);
                #pragma unroll
                for (int qc = 0; qc < 2; qc++)
                    Lacc[qc] = __builtin_amdgcn_mfma_f32_16x16x32_bf16(ones, pfr[qc], Lacc[qc], 0, 0, 0);
                __builtin_amdgcn_s_setprio(0);
            }
        }
        // rotate
        if (sc < 7) {
            #pragma unroll
            for (int mf = 0; mf < 4; mf++) kf[mf] = kfn[mf];
        }
        #pragma unroll
        for (int mc = 0; mc < 2; mc++) {
            vCur[mc][0] = vNew[mc][0];
            vCur[mc][1] = vNew[mc][1];
        }
    }
    // epilogue: PV(7) from buf 1
    #pragma unroll
    for (int mc = 0; mc < 2; mc++) {
        s8v pfr[2];
        #pragma unroll
        for (int qc = 0; qc < 2; qc++)
            pfr[qc] = *(const s8v*)((const char*)&Pq[w][1][qc * 16 + lo4][0] + ((mc * 64 + quad * 16) ^ swz));
        __builtin_amdgcn_s_setprio(1);
        #pragma unroll
        for (int df = 0; df < 2; df++)
            #pragma unroll
            for (int qc = 0; qc < 2; qc++)
                oacc[df][qc] = __builtin_amdgcn_mfma_f32_16x16x32_bf16(vCur[mc][df], pfr[qc], oacc[df][qc], 0, 0, 0);
        #pragma unroll
        for (int qc = 0; qc < 2; qc++)
            Lacc[qc] = __builtin_amdgcn_mfma_f32_16x16x32_bf16(ones, pfr[qc], Lacc[qc], 0, 0, 0);
        __builtin_amdgcn_s_setprio(0);
    }
    if (quad == 0) {
        size_t lb = (((size_t)(spl * 2 + bB) * 4 + g) * 8 + h) * 1024 + n0 + w * 32;
        Lpart[lb + lo4] = Lacc[0][0];
        Lpart[lb + 16 + lo4] = Lacc[1][0];
    }
    #pragma unroll
    for (int qc = 0; qc < 2; qc++)
        #pragma unroll
        for (int df = 0; df < 2; df++) {
            int pb = df * 2 + (quad >> 1);
            uint2 ov;
            ov.x = trunc2(oacc[df][qc][0], oacc[df][qc][1]);
            ov.y = trunc2(oacc[df][qc][2], oacc[df][qc][3]);
            *(uint2*)(Opart + ((size_t)(spl * 2 + bB) * 4096 + pb * 1024 + n0 + w * 32 + qc * 16 + lo4) * 256
                      + g * 64 + h * 8 + (quad & 1) * 4) = ov;
        }
}

// Fused combine+pe+proj+m1+m2 (R17 form, best verified): stage 3 K=320 (mh cols
// 320-383 exactly zero: Wm1 pad rows + bpad zero -> silu(0)=0, Wm2 pad cols zero).
__global__ __launch_bounds__(512) void mlp3_kernel(
    const unsigned short* __restrict__ Opart, const float* __restrict__ Lpart,
    const unsigned short* __restrict__ vC, const float* __restrict__ wpeT,
    const float* __restrict__ spe, const float* __restrict__ bpe,
    const float* __restrict__ x,
    const unsigned short* __restrict__ Wp, const float* __restrict__ bp,
    const unsigned short* __restrict__ Wm1, const float* __restrict__ bm1p,
    const unsigned short* __restrict__ Wm2, const float* __restrict__ bm2,
    float* __restrict__ out)
{
    __shared__ unsigned short bufA[16][392];  // [p][c]: attpe(256) then mh(384)
    __shared__ unsigned short bufX[16][264];  // [p][o]: x1 bf16
    const int tid = threadIdx.x, lane = tid & 63, wv = tid >> 6;   // wv 0..7
    const int lo4 = lane & 15, quad = lane >> 4;
    const int p0 = blockIdx.x * 16, bB = blockIdx.y;

    {   // fused attpe: combine Opart/Lpart + depthwise pe -> bufA [16p][256c]
        int row = tid >> 5, cg = (tid & 31) * 8;
        int p = p0 + row;
        int g = cg >> 6, h = (cg >> 3) & 7;
        int na = p & 1023;
        float L = 0.f;
        float o[8] = {};
        #pragma unroll
        for (int spl = 0; spl < 2; spl++) {
            L += Lpart[(((size_t)(spl * 2 + bB) * 4 + g) * 8 + h) * 1024 + na];
            uint4 v = *(const uint4*)(Opart + ((size_t)(spl * 2 + bB) * 4096 + p) * 256 + cg);
            unsigned short tmp[8]; *(uint4*)tmp = v;
            #pragma unroll
            for (int j = 0; j < 8; j++) o[j] += bf2f(tmp[j]);
        }
        float inv = 1.f / L;
        int hh = p >> 6, ww = p & 63;
        float pe[8] = {};
        for (int di = -1; di <= 1; di++) {
            int h2 = hh + di;
            if (h2 < 0 || h2 > 63) continue;
            for (int dj = -1; dj <= 1; dj++) {
                int w2 = ww + dj;
                if (w2 < 0 || w2 > 63) continue;
                uint4 vv = *(const uint4*)(vC + ((size_t)(bB * 4096 + h2 * 64 + w2)) * 256 + cg);
                unsigned short tmp[8]; *(uint4*)tmp = vv;
                int k = (di + 1) * 3 + (dj + 1);
                float4 wa = *(const float4*)&wpeT[k * 256 + cg];
                float4 wb = *(const float4*)&wpeT[k * 256 + cg + 4];
                float ww8[8] = {wa.x, wa.y, wa.z, wa.w, wb.x, wb.y, wb.z, wb.w};
                #pragma unroll
                for (int j = 0; j < 8; j++)
                    pe[j] = fmaf(bf2f(tmp[j]), ww8[j], pe[j]);
            }
        }
        float4 sa = *(const float4*)&spe[cg];
        float4 sb = *(const float4*)&spe[cg + 4];
        float4 b0 = *(const float4*)&bpe[cg];
        float4 b1 = *(const float4*)&bpe[cg + 4];
        float sv8[8] = {sa.x, sa.y, sa.z, sa.w, sb.x, sb.y, sb.z, sb.w};
        float bv8[8] = {b0.x, b0.y, b0.z, b0.w, b1.x, b1.y, b1.z, b1.w};
        unsigned short ob8[8];
        #pragma unroll
        for (int j = 0; j < 8; j++)
            ob8[j] = f2bf(o[j] * inv + pe[j] * sv8[j] + bv8[j]);
        *(uint4*)&bufA[row][cg] = *(uint4*)ob8;
    }
    __syncthreads();

    // ---- stage 1: x1 = x + proj(attpe); wave o-range wv*32..+31, K=256
    {
        f4v acc[2] = {(f4v){0.f, 0.f, 0.f, 0.f}, (f4v){0.f, 0.f, 0.f, 0.f}};
        #pragma unroll
        for (int kk = 0; kk < 8; kk++) {
            s8v bx = *(const s8v*)&bufA[lo4][kk * 32 + quad * 8];
            #pragma unroll
            for (int of = 0; of < 2; of++) {
                s8v af = *(const s8v*)(Wp + (size_t)(wv * 32 + of * 16 + lo4) * 256 + kk * 32 + quad * 8);
                acc[of] = __builtin_amdgcn_mfma_f32_16x16x32_bf16(af, bx, acc[of], 0, 0, 0);
            }
        }
        #pragma unroll
        for (int of = 0; of < 2; of++) {
            int ob = wv * 32 + of * 16 + quad * 4;
            float4 bb = *(const float4*)&bp[ob];
            float bbv[4] = {bb.x, bb.y, bb.z, bb.w};
            int p = p0 + lo4;
            unsigned short b4[4];
            #pragma unroll
            for (int r = 0; r < 4; r++) {
                float y = acc[of][r] + bbv[r] + x[((size_t)(bB * 256 + ob + r)) * 4096 + p];
                b4[r] = f2bf(y);
            }
            *(ushort4*)&bufX[lo4][ob] = *(ushort4*)b4;
        }
    }
    __syncthreads();

    // ---- stage 2: mh = silu(m1(x1)); wave o-range wv*48..+47, K=256
    {
        f4v acc[3] = {(f4v){0.f, 0.f, 0.f, 0.f}, (f4v){0.f, 0.f, 0.f, 0.f}, (f4v){0.f, 0.f, 0.f, 0.f}};
        #pragma unroll
        for (int kk = 0; kk < 8; kk++) {
            s8v bx = *(const s8v*)&bufX[lo4][kk * 32 + quad * 8];
            #pragma unroll
            for (int of = 0; of < 3; of++) {
                s8v af = *(const s8v*)(Wm1 + (size_t)(wv * 48 + of * 16 + lo4) * 256 + kk * 32 + quad * 8);
                acc[of] = __builtin_amdgcn_mfma_f32_16x16x32_bf16(af, bx, acc[of], 0, 0, 0);
            }
        }
        #pragma unroll
        for (int of = 0; of < 3; of++) {
            int ob = wv * 48 + of * 16 + quad * 4;
            float4 bb = *(const float4*)&bm1p[ob];
            float bbv[4] = {bb.x, bb.y, bb.z, bb.w};
            unsigned short b4[4];
            #pragma unroll
            for (int r = 0; r < 4; r++) {
                float y = acc[of][r] + bbv[r];
                y = y / (1.f + __expf(-y));
                b4[r] = f2bf(y);
            }
            *(ushort4*)&bufA[lo4][ob] = *(ushort4*)b4;
        }
    }
    __syncthreads();

    // ---- stage 3: out = x1 + m2(mh); wave o-range wv*32..+31, K=320 (cols 320-383
    // of Wm2 and mh are exactly zero — dead K-tiles skipped), transposed stores
    {
        f4v acc[2] = {(f4v){0.f, 0.f, 0.f, 0.f}, (f4v){0.f, 0.f, 0.f, 0.f}};
        #pragma unroll
        for (int kk = 0; kk < 10; kk++) {
            s8v bx = *(const s8v*)&bufA[lo4][kk * 32 + quad * 8];
            #pragma unroll
            for (int of = 0; of < 2; of++) {
                s8v af = *(const s8v*)(Wm2 + (size_t)(wv * 32 + of * 16 + lo4) * 384 + kk * 32 + quad * 8);
                acc[of] = __builtin_amdgcn_mfma_f32_16x16x32_bf16(af, bx, acc[of], 0, 0, 0);
            }
        }
        #pragma unroll
        for (int of = 0; of < 2; of++) {
            int ob = wv * 32 + of * 16 + quad * 4;
            float4 bb = *(const float4*)&bm2[ob];
            float bbv[4] = {bb.x, bb.y, bb.z, bb.w};
            ushort4 x1v = *(const ushort4*)&bufX[lo4][ob];
            unsigned short x1a[4]; *(ushort4*)x1a = x1v;
            #pragma unroll
            for (int r = 0; r < 4; r++) {
                float y = acc[of][r] + bbv[r] + bf2f(x1a[r]);
                out[((size_t)(bB * 256 + ob + r)) * 4096 + p0 + lo4] = y;
            }
        }
    }
}

extern "C" void kernel_launch(void* const* d_in, const int* in_sizes, int n_in,
                              void* d_out, int out_size, void* d_ws, size_t ws_size,
                              hipStream_t stream)
{
    const float* x      = (const float*)d_in[0];
    const float* w_qk   = (const float*)d_in[1];
    const float* s_qk   = (const float*)d_in[2];
    const float* b_qk   = (const float*)d_in[3];
    const float* w_v    = (const float*)d_in[4];
    const float* s_v    = (const float*)d_in[5];
    const float* b_v    = (const float*)d_in[6];
    const float* w_pe   = (const float*)d_in[7];
    const float* s_pe   = (const float*)d_in[8];
    const float* b_pe   = (const float*)d_in[9];
    const float* w_proj = (const float*)d_in[10];
    const float* s_proj = (const float*)d_in[11];
    const float* b_proj = (const float*)d_in[12];
    const float* w_m1   = (const float*)d_in[13];
    const float* s_m1   = (const float*)d_in[14];
    const float* b_m1   = (const float*)d_in[15];
    const float* w_m2   = (const float*)d_in[16];
    const float* s_m2   = (const float*)d_in[17];
    const float* b_m2   = (const float*)d_in[18];
    float* out = (float*)d_out;

    const size_t NA = (size_t)2 * 4096 * 256;     // 2,097,152
    unsigned short* vC   = (unsigned short*)d_ws; // bf16 [b][p][256] (V only)
    unsigned short* qP   = vC + NA;               // bf16 packed [b][g][h][1024][4][8]
    unsigned short* kP   = qP + NA;               // bf16 packed [b][g][h][1024][4][8]
    unsigned short* Opart = kP + NA;              // bf16 [2][b][p][256]
    float* Lpart = (float*)(Opart + 2 * NA);      // fp32 [2][b][4][8][1024]
    unsigned short* vT   = (unsigned short*)(Lpart + 131072);  // bf16 [b][256][4096]
    unsigned short* Wqkv = vT + NA;
    unsigned short* Wp   = Wqkv + 196608;
    unsigned short* Wm1  = Wp + 65536;
    unsigned short* Wm2  = Wm1 + 98304;
    float* bpad = (float*)(Wm2 + 98304);
    float* bqv  = bpad + 384;
    float* wpeT = bqv + 768;                       // fp32 [9][256]

    dim3 blk(256);
    wconv_kernel<<<dim3(1806), blk, 0, stream>>>(
        w_qk, s_qk, b_qk, w_v, s_v, b_v, w_proj, s_proj,
        w_m1, s_m1, b_m1, w_m2, s_m2, w_pe,
        Wqkv, Wp, Wm1, Wm2, bpad, bqv, wpeT);

    mmqkv_kernel<<<dim3(64, 6, 2), blk, 0, stream>>>(x, Wqkv, bqv, qP, kP, vC, vT);

    attn_kernel<<<dim3(16, 8, 8), blk, 0, stream>>>(qP, kP, vT, Opart, Lpart);

    // fused combine + pe + proj + m1 + m2 (+ both residuals), out transposed fp32
    mlp3_kernel<<<dim3(256, 2), dim3(512), 0, stream>>>(
        Opart, Lpart, vC, wpeT, s_pe, b_pe,
        x, Wp, b_proj, Wm1, bpad, Wm2, b_m2, out);
}

// Round 20
// 171.747 us; speedup vs baseline: 1.0026x; 1.0026x over previous
//
#include <hip/hip_runtime.h>

typedef __attribute__((ext_vector_type(8))) short s8v;   // 8 bf16 (4 VGPRs) MFMA A/B frag
typedef __attribute__((ext_vector_type(4))) float f4v;   // MFMA C/D frag

#define QSC (0.17677669529663687f * 1.4426950408889634f)  // 1/sqrt(32) * log2(e), folded into q

__device__ __forceinline__ unsigned short f2bf(float x) {
    unsigned u = __float_as_uint(x);
    return (unsigned short)((u + 0x7fffu + ((u >> 16) & 1u)) >> 16);  // RNE
}
__device__ __forceinline__ float bf2f(unsigned short h) {
    return __uint_as_float(((unsigned)h) << 16);
}
// truncation pack (round-toward-zero; P>=0 and O/L use the same truncated P)
__device__ __forceinline__ unsigned trunc2(float a, float b) {
    return (__float_as_uint(b) & 0xffff0000u) | (__float_as_uint(a) >> 16);
}

// One-shot weight prep (+ wpe transpose to [9][256])
__global__ __launch_bounds__(256) void wconv_kernel(
    const float* __restrict__ wqk, const float* __restrict__ sqk, const float* __restrict__ bqk,
    const float* __restrict__ wv,  const float* __restrict__ sv,  const float* __restrict__ bv,
    const float* __restrict__ wprj, const float* __restrict__ sprj,
    const float* __restrict__ wm1, const float* __restrict__ sm1, const float* __restrict__ bm1,
    const float* __restrict__ wm2, const float* __restrict__ sm2,
    const float* __restrict__ wpe9,
    unsigned short* __restrict__ Wqkv, unsigned short* __restrict__ Wp,
    unsigned short* __restrict__ Wm1,  unsigned short* __restrict__ Wm2,
    float* __restrict__ bpad, float* __restrict__ bqv, float* __restrict__ wpeT)
{
    int i = blockIdx.x * 256 + threadIdx.x;
    if (i < 196608) {                       // Wqkv [768][256]
        int o = i >> 8, c = i & 255;
        float w;
        if (o < 512) { float f = ((o & 127) < 64) ? QSC : 1.f; w = wqk[i] * sqk[o] * f; }
        else          w = wv[(o - 512) * 256 + c] * sv[o - 512];
        Wqkv[i] = f2bf(w);
    } else if (i < 262144) {                // w_proj [256][256]
        int j = i - 196608; int o = j >> 8; Wp[j] = f2bf(wprj[j] * sprj[o]);
    } else if (i < 360448) {                // w_m1 [384pad][256]
        int j = i - 262144; int o = j >> 8, c = j & 255;
        Wm1[j] = (o < 307) ? f2bf(wm1[o * 256 + c] * sm1[o]) : (unsigned short)0;
    } else if (i < 458752) {                // w_m2 [256][384pad]
        int j = i - 360448; int o = j / 384, c = j - o * 384;
        Wm2[j] = (c < 307) ? f2bf(wm2[o * 307 + c] * sm2[o]) : (unsigned short)0;
    } else if (i < 459136) {                // b_m1 padded to 384
        int j = i - 458752; bpad[j] = (j < 307) ? bm1[j] : 0.f;
    } else if (i < 459904) {                // bqv[768]
        int j = i - 459136;
        bqv[j] = (j < 512) ? (bqk[j] * (((j & 127) < 64) ? QSC : 1.f)) : bv[j - 512];
    } else if (i < 462208) {                // wpeT [9][256]
        int j = i - 459904; int k = j >> 8, c = j & 255;
        wpeT[j] = wpe9[c * 9 + k];
    }
}

// Fused transpose + qkv GEMM (R16 form: LDS double-buffer, one barrier per kc,
// next-tile loads issued after the barrier to overlap MFMA; measured ~= R8).
__global__ __launch_bounds__(256) void mmqkv_kernel(
    const float* __restrict__ X, const unsigned short* __restrict__ Wb,
    const float* __restrict__ bi,
    unsigned short* __restrict__ qP, unsigned short* __restrict__ kP,
    unsigned short* __restrict__ vC, unsigned short* __restrict__ vT)
{
    __shared__ unsigned short Ap[2][64][40];
    __shared__ unsigned short Wt[2][128][40];
    const int tid = threadIdx.x, lane = tid & 63, wv = tid >> 6;
    const int lo4 = lane & 15, quad = lane >> 4;
    const int p0 = blockIdx.x * 64, o0 = blockIdx.y * 128, bB = blockIdx.z;
    const int ph = (wv & 1) * 32, oh = (wv >> 1) * 64;
    const int c2 = tid & 15, pg = tid >> 4;
    const int oW0 = tid >> 2, oW1 = (tid + 256) >> 2;
    const int cW = (tid & 3) * 8;
    const float* xb = X + (size_t)bB * 256 * 4096;

    f4v acc[4][2];
    #pragma unroll
    for (int i = 0; i < 4; i++)
        #pragma unroll
        for (int j = 0; j < 2; j++)
            acc[i][j] = (f4v){0.f, 0.f, 0.f, 0.f};

    // tile 0: load + stage into buf 0
    {
        float4 fa = *(const float4*)&xb[(size_t)(2 * c2) * 4096 + p0 + pg * 4];
        float4 fb = *(const float4*)&xb[(size_t)(2 * c2 + 1) * 4096 + p0 + pg * 4];
        uint4 wReg0 = *(const uint4*)(Wb + (size_t)(o0 + oW0) * 256 + cW);
        uint4 wReg1 = *(const uint4*)(Wb + (size_t)(o0 + oW1) * 256 + cW);
        float av[4] = {fa.x, fa.y, fa.z, fa.w};
        float bv2[4] = {fb.x, fb.y, fb.z, fb.w};
        #pragma unroll
        for (int i = 0; i < 4; i++)
            *(unsigned*)&Ap[0][pg * 4 + i][2 * c2] =
                (unsigned)f2bf(av[i]) | ((unsigned)f2bf(bv2[i]) << 16);
        *(uint4*)&Wt[0][oW0][cW] = wReg0;
        *(uint4*)&Wt[0][oW1][cW] = wReg1;
    }

    for (int kc = 0; kc < 8; kc++) {
        const int cur = kc & 1, nxt = cur ^ 1;
        __syncthreads();                      // buf[cur] staged for all waves
        float4 fa, fb;
        uint4 wReg0, wReg1;
        if (kc < 7) {                         // issue next-tile loads; overlap MFMA
            int k1 = (kc + 1) * 32;
            fa = *(const float4*)&xb[(size_t)(k1 + 2 * c2) * 4096 + p0 + pg * 4];
            fb = *(const float4*)&xb[(size_t)(k1 + 2 * c2 + 1) * 4096 + p0 + pg * 4];
            wReg0 = *(const uint4*)(Wb + (size_t)(o0 + oW0) * 256 + k1 + cW);
            wReg1 = *(const uint4*)(Wb + (size_t)(o0 + oW1) * 256 + k1 + cW);
        }
        s8v af[4], bx[2];
        #pragma unroll
        for (int of = 0; of < 4; of++)
            af[of] = *(const s8v*)&Wt[cur][oh + of * 16 + lo4][quad * 8];
        #pragma unroll
        for (int pf = 0; pf < 2; pf++)
            bx[pf] = *(const s8v*)&Ap[cur][ph + pf * 16 + lo4][quad * 8];
        #pragma unroll
        for (int of = 0; of < 4; of++)
            #pragma unroll
            for (int pf = 0; pf < 2; pf++)
                acc[of][pf] = __builtin_amdgcn_mfma_f32_16x16x32_bf16(af[of], bx[pf], acc[of][pf], 0, 0, 0);
        if (kc < 7) {                         // stage next tile into the other buffer
            float av[4] = {fa.x, fa.y, fa.z, fa.w};
            float bv2[4] = {fb.x, fb.y, fb.z, fb.w};
            #pragma unroll
            for (int i = 0; i < 4; i++)
                *(unsigned*)&Ap[nxt][pg * 4 + i][2 * c2] =
                    (unsigned)f2bf(av[i]) | ((unsigned)f2bf(bv2[i]) << 16);
            *(uint4*)&Wt[nxt][oW0][cW] = wReg0;
            *(uint4*)&Wt[nxt][oW1][cW] = wReg1;
        }
    }
    #pragma unroll
    for (int of = 0; of < 4; of++) {
        int ob = o0 + oh + of * 16 + quad * 4;
        float4 bb = *(const float4*)&bi[ob];
        float bbv[4] = {bb.x, bb.y, bb.z, bb.w};
        #pragma unroll
        for (int pf = 0; pf < 2; pf++) {
            int p = p0 + ph + pf * 16 + lo4;
            unsigned short b4[4];
            #pragma unroll
            for (int r = 0; r < 4; r++) b4[r] = f2bf(acc[of][pf][r] + bbv[r]);
            if (ob < 512) {              // wave-uniform branch (64-wide o-ranges)
                int gg = ob >> 7, rr = ob & 127;
                int hh = (rr & 63) >> 3, j0 = rr & 7;
                unsigned short* dst = (rr >= 64) ? kP : qP;
                *(ushort4*)&dst[((((size_t)(bB * 4 + gg)) * 8 + hh) * 1024 + (p & 1023)) * 32
                                + (p >> 10) * 8 + j0] = *(ushort4*)b4;
            } else {
                *(ushort4*)&vC[((size_t)(bB * 4096 + p)) * 256 + (ob - 512)] = *(ushort4*)b4;
                #pragma unroll
                for (int r = 0; r < 4; r++)
                    vT[((size_t)(bB * 256 + ob - 512 + r)) * 4096 + p] = b4[r];
            }
        }
    }
}

// MFMA area-attention (R8 form — best measured): barrier-free, packed Q/K,
// per-wave DOUBLE-BUFFERED P LDS (XOR-swizzled), spl=2, exp2f builtin.
__global__ __launch_bounds__(256) void attn_kernel(
    const unsigned short* __restrict__ qP, const unsigned short* __restrict__ kP,
    const unsigned short* __restrict__ vT,
    unsigned short* __restrict__ Opart, float* __restrict__ Lpart)
{
    __shared__ unsigned short Pq[4][2][32][64];   // [wave][buf][q][m], rows 128B, XOR-swizzled
    const int tid = threadIdx.x;
    const int w = tid >> 6, lane = tid & 63;
    const int lo4 = lane & 15, quad = lane >> 4;
    const int swz = (lo4 & 7) << 4;               // byte-XOR within 128B row
    const int n0 = blockIdx.z * 128;
    const int h = blockIdx.y;
    const int z = blockIdx.x;                     // 16 = ba(0..7)<<1 | spl
    const int ba = z >> 1, spl = z & 1;
    const int bB = ba >> 2, g = ba & 3;
    const int mbase = spl * 512;

    const unsigned short* qb = qP + (((size_t)(bB * 4) + g) * 8 + h) * 32768;
    const unsigned short* kb = kP + (((size_t)(bB * 4) + g) * 8 + h) * 32768;

    s8v qf[2];
    #pragma unroll
    for (int qc = 0; qc < 2; qc++)
        qf[qc] = *(const s8v*)(qb + (size_t)(n0 + w * 32 + qc * 16 + lo4) * 32 + quad * 8);
    const int dd0 = lo4, dd1 = 16 + lo4;
    const unsigned short* vb0 = vT + ((size_t)(bB * 256 + g * 64 + h * 8 + (dd0 & 7))) * 4096 + (dd0 >> 3) * 1024 + mbase + quad * 8;
    const unsigned short* vb1 = vT + ((size_t)(bB * 256 + g * 64 + h * 8 + (dd1 & 7))) * 4096 + (dd1 >> 3) * 1024 + mbase + quad * 8;

    f4v oacc[2][2], Lacc[2];
    #pragma unroll
    for (int i = 0; i < 2; i++) {
        Lacc[i] = (f4v){0.f, 0.f, 0.f, 0.f};
        #pragma unroll
        for (int j = 0; j < 2; j++)
            oacc[i][j] = (f4v){0.f, 0.f, 0.f, 0.f};
    }
    s8v ones;
    #pragma unroll
    for (int j = 0; j < 8; j++) ones[j] = (short)0x3F80;   // bf16 1.0

    s8v kf[4], vCur[2][2];
    #pragma unroll
    for (int mf = 0; mf < 4; mf++)
        kf[mf] = *(const s8v*)(kb + (size_t)(mbase + mf * 16 + lo4) * 32 + quad * 8);

    #pragma unroll
    for (int sc = 0; sc < 8; sc++) {
        // V for chunk sc (consumed by PV(sc) next iteration / epilogue)
        s8v vNew[2][2];
        #pragma unroll
        for (int mc = 0; mc < 2; mc++) {
            vNew[mc][0] = *(const s8v*)(vb0 + sc * 64 + mc * 32);
            vNew[mc][1] = *(const s8v*)(vb1 + sc * 64 + mc * 32);
        }
        // K for chunk sc+1
        s8v kfn[4];
        if (sc < 7) {
            #pragma unroll
            for (int mf = 0; mf < 4; mf++)
                kfn[mf] = *(const s8v*)(kb + (size_t)(mbase + (sc + 1) * 64 + mf * 16 + lo4) * 32 + quad * 8);
        }
        // QK(sc)
        f4v sT[4][2];
        __builtin_amdgcn_s_setprio(1);
        #pragma unroll
        for (int mf = 0; mf < 4; mf++)
            #pragma unroll
            for (int qc = 0; qc < 2; qc++)
                sT[mf][qc] = __builtin_amdgcn_mfma_f32_16x16x32_bf16(kf[mf], qf[qc], (f4v){0.f, 0.f, 0.f, 0.f}, 0, 0, 0);
        __builtin_amdgcn_s_setprio(0);
        // exp(sc) + write P(sc) into buf sc&1
        #pragma unroll
        for (int qc = 0; qc < 2; qc++) {
            char* prow = (char*)&Pq[w][sc & 1][qc * 16 + lo4][0];
            #pragma unroll
            for (int mf = 0; mf < 4; mf++) {
                float p0v = __builtin_amdgcn_exp2f(sT[mf][qc][0]);
                float p1v = __builtin_amdgcn_exp2f(sT[mf][qc][1]);
                float p2v = __builtin_amdgcn_exp2f(sT[mf][qc][2]);
                float p3v = __builtin_amdgcn_exp2f(sT[mf][qc][3]);
                uint2 pk;
                pk.x = trunc2(p0v, p1v);
                pk.y = trunc2(p2v, p3v);
                *(uint2*)(prow + ((mf * 32 + quad * 8) ^ swz)) = pk;
            }
        }
        // PV(sc-1) from the other buffer, V loaded last iteration
        if (sc > 0) {
            #pragma unroll
            for (int mc = 0; mc < 2; mc++) {
                s8v pfr[2];
                #pragma unroll
                for (int qc = 0; qc < 2; qc++)
                    pfr[qc] = *(const s8v*)((const char*)&Pq[w][(sc - 1) & 1][qc * 16 + lo4][0] + ((mc * 64 + quad * 16) ^ swz));
                __builtin_amdgcn_s_setprio(1);
                #pragma unroll
                for (int df = 0; df < 2; df++)
                    #pragma unroll
                    for (int qc = 0; qc < 2; qc++)
                        oacc[df][qc] = __builtin_amdgcn_mfma_f32_16x16x32_bf16(vCur[mc][df], pfr[qc], oacc[df][qc], 0, 0, 0);
                #pragma unroll
                for (int qc = 0; qc < 2; qc++)
                    Lacc[qc] = __builtin_amdgcn_mfma_f32_16x16x32_bf16(ones, pfr[qc], Lacc[qc], 0, 0, 0);
                __builtin_amdgcn_s_setprio(0);
            }
        }
        // rotate
        if (sc < 7) {
            #pragma unroll
            for (int mf = 0; mf < 4; mf++) kf[mf] = kfn[mf];
        }
        #pragma unroll
        for (int mc = 0; mc < 2; mc++) {
            vCur[mc][0] = vNew[mc][0];
            vCur[mc][1] = vNew[mc][1];
        }
    }
    // epilogue: PV(7) from buf 1
    #pragma unroll
    for (int mc = 0; mc < 2; mc++) {
        s8v pfr[2];
        #pragma unroll
        for (int qc = 0; qc < 2; qc++)
            pfr[qc] = *(const s8v*)((const char*)&Pq[w][1][qc * 16 + lo4][0] + ((mc * 64 + quad * 16) ^ swz));
        __builtin_amdgcn_s_setprio(1);
        #pragma unroll
        for (int df = 0; df < 2; df++)
            #pragma unroll
            for (int qc = 0; qc < 2; qc++)
                oacc[df][qc] = __builtin_amdgcn_mfma_f32_16x16x32_bf16(vCur[mc][df], pfr[qc], oacc[df][qc], 0, 0, 0);
        #pragma unroll
        for (int qc = 0; qc < 2; qc++)
            Lacc[qc] = __builtin_amdgcn_mfma_f32_16x16x32_bf16(ones, pfr[qc], Lacc[qc], 0, 0, 0);
        __builtin_amdgcn_s_setprio(0);
    }
    if (quad == 0) {
        size_t lb = (((size_t)(spl * 2 + bB) * 4 + g) * 8 + h) * 1024 + n0 + w * 32;
        Lpart[lb + lo4] = Lacc[0][0];
        Lpart[lb + 16 + lo4] = Lacc[1][0];
    }
    #pragma unroll
    for (int qc = 0; qc < 2; qc++)
        #pragma unroll
        for (int df = 0; df < 2; df++) {
            int pb = df * 2 + (quad >> 1);
            uint2 ov;
            ov.x = trunc2(oacc[df][qc][0], oacc[df][qc][1]);
            ov.y = trunc2(oacc[df][qc][2], oacc[df][qc][3]);
            *(uint2*)(Opart + ((size_t)(spl * 2 + bB) * 4096 + pb * 1024 + n0 + w * 32 + qc * 16 + lo4) * 256
                      + g * 64 + h * 8 + (quad & 1) * 4) = ov;
        }
}

// Fused combine+pe+proj+m1+m2 (R17 form, best verified): stage 3 K=320 (mh cols
// 320-383 exactly zero: Wm1 pad rows + bpad zero -> silu(0)=0, Wm2 pad cols zero).
__global__ __launch_bounds__(512) void mlp3_kernel(
    const unsigned short* __restrict__ Opart, const float* __restrict__ Lpart,
    const unsigned short* __restrict__ vC, const float* __restrict__ wpeT,
    const float* __restrict__ spe, const float* __restrict__ bpe,
    const float* __restrict__ x,
    const unsigned short* __restrict__ Wp, const float* __restrict__ bp,
    const unsigned short* __restrict__ Wm1, const float* __restrict__ bm1p,
    const unsigned short* __restrict__ Wm2, const float* __restrict__ bm2,
    float* __restrict__ out)
{
    __shared__ unsigned short bufA[16][392];  // [p][c]: attpe(256) then mh(384)
    __shared__ unsigned short bufX[16][264];  // [p][o]: x1 bf16
    const int tid = threadIdx.x, lane = tid & 63, wv = tid >> 6;   // wv 0..7
    const int lo4 = lane & 15, quad = lane >> 4;
    const int p0 = blockIdx.x * 16, bB = blockIdx.y;

    {   // fused attpe: combine Opart/Lpart + depthwise pe -> bufA [16p][256c]
        int row = tid >> 5, cg = (tid & 31) * 8;
        int p = p0 + row;
        int g = cg >> 6, h = (cg >> 3) & 7;
        int na = p & 1023;
        float L = 0.f;
        float o[8] = {};
        #pragma unroll
        for (int spl = 0; spl < 2; spl++) {
            L += Lpart[(((size_t)(spl * 2 + bB) * 4 + g) * 8 + h) * 1024 + na];
            uint4 v = *(const uint4*)(Opart + ((size_t)(spl * 2 + bB) * 4096 + p) * 256 + cg);
            unsigned short tmp[8]; *(uint4*)tmp = v;
            #pragma unroll
            for (int j = 0; j < 8; j++) o[j] += bf2f(tmp[j]);
        }
        float inv = 1.f / L;
        int hh = p >> 6, ww = p & 63;
        float pe[8] = {};
        for (int di = -1; di <= 1; di++) {
            int h2 = hh + di;
            if (h2 < 0 || h2 > 63) continue;
            for (int dj = -1; dj <= 1; dj++) {
                int w2 = ww + dj;
                if (w2 < 0 || w2 > 63) continue;
                uint4 vv = *(const uint4*)(vC + ((size_t)(bB * 4096 + h2 * 64 + w2)) * 256 + cg);
                unsigned short tmp[8]; *(uint4*)tmp = vv;
                int k = (di + 1) * 3 + (dj + 1);
                float4 wa = *(const float4*)&wpeT[k * 256 + cg];
                float4 wb = *(const float4*)&wpeT[k * 256 + cg + 4];
                float ww8[8] = {wa.x, wa.y, wa.z, wa.w, wb.x, wb.y, wb.z, wb.w};
                #pragma unroll
                for (int j = 0; j < 8; j++)
                    pe[j] = fmaf(bf2f(tmp[j]), ww8[j], pe[j]);
            }
        }
        float4 sa = *(const float4*)&spe[cg];
        float4 sb = *(const float4*)&spe[cg + 4];
        float4 b0 = *(const float4*)&bpe[cg];
        float4 b1 = *(const float4*)&bpe[cg + 4];
        float sv8[8] = {sa.x, sa.y, sa.z, sa.w, sb.x, sb.y, sb.z, sb.w};
        float bv8[8] = {b0.x, b0.y, b0.z, b0.w, b1.x, b1.y, b1.z, b1.w};
        unsigned short ob8[8];
        #pragma unroll
        for (int j = 0; j < 8; j++)
            ob8[j] = f2bf(o[j] * inv + pe[j] * sv8[j] + bv8[j]);
        *(uint4*)&bufA[row][cg] = *(uint4*)ob8;
    }
    __syncthreads();

    // ---- stage 1: x1 = x + proj(attpe); wave o-range wv*32..+31, K=256
    {
        f4v acc[2] = {(f4v){0.f, 0.f, 0.f, 0.f}, (f4v){0.f, 0.f, 0.f, 0.f}};
        #pragma unroll
        for (int kk = 0; kk < 8; kk++) {
            s8v bx = *(const s8v*)&bufA[lo4][kk * 32 + quad * 8];
            #pragma unroll
            for (int of = 0; of < 2; of++) {
                s8v af = *(const s8v*)(Wp + (size_t)(wv * 32 + of * 16 + lo4) * 256 + kk * 32 + quad * 8);
                acc[of] = __builtin_amdgcn_mfma_f32_16x16x32_bf16(af, bx, acc[of], 0, 0, 0);
            }
        }
        #pragma unroll
        for (int of = 0; of < 2; of++) {
            int ob = wv * 32 + of * 16 + quad * 4;
            float4 bb = *(const float4*)&bp[ob];
            float bbv[4] = {bb.x, bb.y, bb.z, bb.w};
            int p = p0 + lo4;
            unsigned short b4[4];
            #pragma unroll
            for (int r = 0; r < 4; r++) {
                float y = acc[of][r] + bbv[r] + x[((size_t)(bB * 256 + ob + r)) * 4096 + p];
                b4[r] = f2bf(y);
            }
            *(ushort4*)&bufX[lo4][ob] = *(ushort4*)b4;
        }
    }
    __syncthreads();

    // ---- stage 2: mh = silu(m1(x1)); wave o-range wv*48..+47, K=256
    {
        f4v acc[3] = {(f4v){0.f, 0.f, 0.f, 0.f}, (f4v){0.f, 0.f, 0.f, 0.f}, (f4v){0.f, 0.f, 0.f, 0.f}};
        #pragma unroll
        for (int kk = 0; kk < 8; kk++) {
            s8v bx = *(const s8v*)&bufX[lo4][kk * 32 + quad * 8];
            #pragma unroll
            for (int of = 0; of < 3; of++) {
                s8v af = *(const s8v*)(Wm1 + (size_t)(wv * 48 + of * 16 + lo4) * 256 + kk * 32 + quad * 8);
                acc[of] = __builtin_amdgcn_mfma_f32_16x16x32_bf16(af, bx, acc[of], 0, 0, 0);
            }
        }
        #pragma unroll
        for (int of = 0; of < 3; of++) {
            int ob = wv * 48 + of * 16 + quad * 4;
            float4 bb = *(const float4*)&bm1p[ob];
            float bbv[4] = {bb.x, bb.y, bb.z, bb.w};
            unsigned short b4[4];
            #pragma unroll
            for (int r = 0; r < 4; r++) {
                float y = acc[of][r] + bbv[r];
                y = y / (1.f + __expf(-y));
                b4[r] = f2bf(y);
            }
            *(ushort4*)&bufA[lo4][ob] = *(ushort4*)b4;
        }
    }
    __syncthreads();

    // ---- stage 3: out = x1 + m2(mh); wave o-range wv*32..+31, K=320 (cols 320-383
    // of Wm2 and mh are exactly zero — dead K-tiles skipped), transposed stores
    {
        f4v acc[2] = {(f4v){0.f, 0.f, 0.f, 0.f}, (f4v){0.f, 0.f, 0.f, 0.f}};
        #pragma unroll
        for (int kk = 0; kk < 10; kk++) {
            s8v bx = *(const s8v*)&bufA[lo4][kk * 32 + quad * 8];
            #pragma unroll
            for (int of = 0; of < 2; of++) {
                s8v af = *(const s8v*)(Wm2 + (size_t)(wv * 32 + of * 16 + lo4) * 384 + kk * 32 + quad * 8);
                acc[of] = __builtin_amdgcn_mfma_f32_16x16x32_bf16(af, bx, acc[of], 0, 0, 0);
            }
        }
        #pragma unroll
        for (int of = 0; of < 2; of++) {
            int ob = wv * 32 + of * 16 + quad * 4;
            float4 bb = *(const float4*)&bm2[ob];
            float bbv[4] = {bb.x, bb.y, bb.z, bb.w};
            ushort4 x1v = *(const ushort4*)&bufX[lo4][ob];
            unsigned short x1a[4]; *(ushort4*)x1a = x1v;
            #pragma unroll
            for (int r = 0; r < 4; r++) {
                float y = acc[of][r] + bbv[r] + bf2f(x1a[r]);
                out[((size_t)(bB * 256 + ob + r)) * 4096 + p0 + lo4] = y;
            }
        }
    }
}

extern "C" void kernel_launch(void* const* d_in, const int* in_sizes, int n_in,
                              void* d_out, int out_size, void* d_ws, size_t ws_size,
                              hipStream_t stream)
{
    const float* x      = (const float*)d_in[0];
    const float* w_qk   = (const float*)d_in[1];
    const float* s_qk   = (const float*)d_in[2];
    const float* b_qk   = (const float*)d_in[3];
    const float* w_v    = (const float*)d_in[4];
    const float* s_v    = (const float*)d_in[5];
    const float* b_v    = (const float*)d_in[6];
    const float* w_pe   = (const float*)d_in[7];
    const float* s_pe   = (const float*)d_in[8];
    const float* b_pe   = (const float*)d_in[9];
    const float* w_proj = (const float*)d_in[10];
    const float* s_proj = (const float*)d_in[11];
    const float* b_proj = (const float*)d_in[12];
    const float* w_m1   = (const float*)d_in[13];
    const float* s_m1   = (const float*)d_in[14];
    const float* b_m1   = (const float*)d_in[15];
    const float* w_m2   = (const float*)d_in[16];
    const float* s_m2   = (const float*)d_in[17];
    const float* b_m2   = (const float*)d_in[18];
    float* out = (float*)d_out;

    const size_t NA = (size_t)2 * 4096 * 256;     // 2,097,152
    unsigned short* vC   = (unsigned short*)d_ws; // bf16 [b][p][256] (V only)
    unsigned short* qP   = vC + NA;               // bf16 packed [b][g][h][1024][4][8]
    unsigned short* kP   = qP + NA;               // bf16 packed [b][g][h][1024][4][8]
    unsigned short* Opart = kP + NA;              // bf16 [2][b][p][256]
    float* Lpart = (float*)(Opart + 2 * NA);      // fp32 [2][b][4][8][1024]
    unsigned short* vT   = (unsigned short*)(Lpart + 131072);  // bf16 [b][256][4096]
    unsigned short* Wqkv = vT + NA;
    unsigned short* Wp   = Wqkv + 196608;
    unsigned short* Wm1  = Wp + 65536;
    unsigned short* Wm2  = Wm1 + 98304;
    float* bpad = (float*)(Wm2 + 98304);
    float* bqv  = bpad + 384;
    float* wpeT = bqv + 768;                       // fp32 [9][256]

    dim3 blk(256);
    wconv_kernel<<<dim3(1806), blk, 0, stream>>>(
        w_qk, s_qk, b_qk, w_v, s_v, b_v, w_proj, s_proj,
        w_m1, s_m1, b_m1, w_m2, s_m2, w_pe,
        Wqkv, Wp, Wm1, Wm2, bpad, bqv, wpeT);

    mmqkv_kernel<<<dim3(64, 6, 2), blk, 0, stream>>>(x, Wqkv, bqv, qP, kP, vC, vT);

    attn_kernel<<<dim3(16, 8, 8), blk, 0, stream>>>(qP, kP, vT, Opart, Lpart);

    // fused combine + pe + proj + m1 + m2 (+ both residuals), out transposed fp32
    mlp3_kernel<<<dim3(256, 2), dim3(512), 0, stream>>>(
        Opart, Lpart, vC, wpeT, s_pe, b_pe,
        x, Wp, b_proj, Wm1, bpad, Wm2, b_m2, out);
}

// Round 21
// 170.959 us; speedup vs baseline: 1.0072x; 1.0046x over previous
//
#include <hip/hip_runtime.h>

typedef __attribute__((ext_vector_type(8))) short s8v;   // 8 bf16 (4 VGPRs) MFMA A/B frag
typedef __attribute__((ext_vector_type(4))) float f4v;   // MFMA C/D frag

#define QSC (0.17677669529663687f * 1.4426950408889634f)  // 1/sqrt(32) * log2(e), folded into q

__device__ __forceinline__ unsigned short f2bf(float x) {
    unsigned u = __float_as_uint(x);
    return (unsigned short)((u + 0x7fffu + ((u >> 16) & 1u)) >> 16);  // RNE
}
__device__ __forceinline__ float bf2f(unsigned short h) {
    return __uint_as_float(((unsigned)h) << 16);
}
// truncation pack (round-toward-zero; P>=0 and O/L use the same truncated P)
__device__ __forceinline__ unsigned trunc2(float a, float b) {
    return (__float_as_uint(b) & 0xffff0000u) | (__float_as_uint(a) >> 16);
}

// One-shot weight prep (+ wpe transpose to [9][256])
__global__ __launch_bounds__(256) void wconv_kernel(
    const float* __restrict__ wqk, const float* __restrict__ sqk, const float* __restrict__ bqk,
    const float* __restrict__ wv,  const float* __restrict__ sv,  const float* __restrict__ bv,
    const float* __restrict__ wprj, const float* __restrict__ sprj,
    const float* __restrict__ wm1, const float* __restrict__ sm1, const float* __restrict__ bm1,
    const float* __restrict__ wm2, const float* __restrict__ sm2,
    const float* __restrict__ wpe9,
    unsigned short* __restrict__ Wqkv, unsigned short* __restrict__ Wp,
    unsigned short* __restrict__ Wm1,  unsigned short* __restrict__ Wm2,
    float* __restrict__ bpad, float* __restrict__ bqv, float* __restrict__ wpeT)
{
    int i = blockIdx.x * 256 + threadIdx.x;
    if (i < 196608) {                       // Wqkv [768][256]
        int o = i >> 8, c = i & 255;
        float w;
        if (o < 512) { float f = ((o & 127) < 64) ? QSC : 1.f; w = wqk[i] * sqk[o] * f; }
        else          w = wv[(o - 512) * 256 + c] * sv[o - 512];
        Wqkv[i] = f2bf(w);
    } else if (i < 262144) {                // w_proj [256][256]
        int j = i - 196608; int o = j >> 8; Wp[j] = f2bf(wprj[j] * sprj[o]);
    } else if (i < 360448) {                // w_m1 [384pad][256]
        int j = i - 262144; int o = j >> 8, c = j & 255;
        Wm1[j] = (o < 307) ? f2bf(wm1[o * 256 + c] * sm1[o]) : (unsigned short)0;
    } else if (i < 458752) {                // w_m2 [256][384pad]
        int j = i - 360448; int o = j / 384, c = j - o * 384;
        Wm2[j] = (c < 307) ? f2bf(wm2[o * 307 + c] * sm2[o]) : (unsigned short)0;
    } else if (i < 459136) {                // b_m1 padded to 384
        int j = i - 458752; bpad[j] = (j < 307) ? bm1[j] : 0.f;
    } else if (i < 459904) {                // bqv[768]
        int j = i - 459136;
        bqv[j] = (j < 512) ? (bqk[j] * (((j & 127) < 64) ? QSC : 1.f)) : bv[j - 512];
    } else if (i < 462208) {                // wpeT [9][256]
        int j = i - 459904; int k = j >> 8, c = j & 255;
        wpeT[j] = wpe9[c * 9 + k];
    }
}

// Fused transpose + qkv GEMM (R16 form: LDS double-buffer, one barrier per kc,
// next-tile loads issued after the barrier to overlap MFMA; measured ~= R8).
__global__ __launch_bounds__(256) void mmqkv_kernel(
    const float* __restrict__ X, const unsigned short* __restrict__ Wb,
    const float* __restrict__ bi,
    unsigned short* __restrict__ qP, unsigned short* __restrict__ kP,
    unsigned short* __restrict__ vC, unsigned short* __restrict__ vT)
{
    __shared__ unsigned short Ap[2][64][40];
    __shared__ unsigned short Wt[2][128][40];
    const int tid = threadIdx.x, lane = tid & 63, wv = tid >> 6;
    const int lo4 = lane & 15, quad = lane >> 4;
    const int p0 = blockIdx.x * 64, o0 = blockIdx.y * 128, bB = blockIdx.z;
    const int ph = (wv & 1) * 32, oh = (wv >> 1) * 64;
    const int c2 = tid & 15, pg = tid >> 4;
    const int oW0 = tid >> 2, oW1 = (tid + 256) >> 2;
    const int cW = (tid & 3) * 8;
    const float* xb = X + (size_t)bB * 256 * 4096;

    f4v acc[4][2];
    #pragma unroll
    for (int i = 0; i < 4; i++)
        #pragma unroll
        for (int j = 0; j < 2; j++)
            acc[i][j] = (f4v){0.f, 0.f, 0.f, 0.f};

    // tile 0: load + stage into buf 0
    {
        float4 fa = *(const float4*)&xb[(size_t)(2 * c2) * 4096 + p0 + pg * 4];
        float4 fb = *(const float4*)&xb[(size_t)(2 * c2 + 1) * 4096 + p0 + pg * 4];
        uint4 wReg0 = *(const uint4*)(Wb + (size_t)(o0 + oW0) * 256 + cW);
        uint4 wReg1 = *(const uint4*)(Wb + (size_t)(o0 + oW1) * 256 + cW);
        float av[4] = {fa.x, fa.y, fa.z, fa.w};
        float bv2[4] = {fb.x, fb.y, fb.z, fb.w};
        #pragma unroll
        for (int i = 0; i < 4; i++)
            *(unsigned*)&Ap[0][pg * 4 + i][2 * c2] =
                (unsigned)f2bf(av[i]) | ((unsigned)f2bf(bv2[i]) << 16);
        *(uint4*)&Wt[0][oW0][cW] = wReg0;
        *(uint4*)&Wt[0][oW1][cW] = wReg1;
    }

    for (int kc = 0; kc < 8; kc++) {
        const int cur = kc & 1, nxt = cur ^ 1;
        __syncthreads();                      // buf[cur] staged for all waves
        float4 fa, fb;
        uint4 wReg0, wReg1;
        if (kc < 7) {                         // issue next-tile loads; overlap MFMA
            int k1 = (kc + 1) * 32;
            fa = *(const float4*)&xb[(size_t)(k1 + 2 * c2) * 4096 + p0 + pg * 4];
            fb = *(const float4*)&xb[(size_t)(k1 + 2 * c2 + 1) * 4096 + p0 + pg * 4];
            wReg0 = *(const uint4*)(Wb + (size_t)(o0 + oW0) * 256 + k1 + cW);
            wReg1 = *(const uint4*)(Wb + (size_t)(o0 + oW1) * 256 + k1 + cW);
        }
        s8v af[4], bx[2];
        #pragma unroll
        for (int of = 0; of < 4; of++)
            af[of] = *(const s8v*)&Wt[cur][oh + of * 16 + lo4][quad * 8];
        #pragma unroll
        for (int pf = 0; pf < 2; pf++)
            bx[pf] = *(const s8v*)&Ap[cur][ph + pf * 16 + lo4][quad * 8];
        #pragma unroll
        for (int of = 0; of < 4; of++)
            #pragma unroll
            for (int pf = 0; pf < 2; pf++)
                acc[of][pf] = __builtin_amdgcn_mfma_f32_16x16x32_bf16(af[of], bx[pf], acc[of][pf], 0, 0, 0);
        if (kc < 7) {                         // stage next tile into the other buffer
            float av[4] = {fa.x, fa.y, fa.z, fa.w};
            float bv2[4] = {fb.x, fb.y, fb.z, fb.w};
            #pragma unroll
            for (int i = 0; i < 4; i++)
                *(unsigned*)&Ap[nxt][pg * 4 + i][2 * c2] =
                    (unsigned)f2bf(av[i]) | ((unsigned)f2bf(bv2[i]) << 16);
            *(uint4*)&Wt[nxt][oW0][cW] = wReg0;
            *(uint4*)&Wt[nxt][oW1][cW] = wReg1;
        }
    }
    #pragma unroll
    for (int of = 0; of < 4; of++) {
        int ob = o0 + oh + of * 16 + quad * 4;
        float4 bb = *(const float4*)&bi[ob];
        float bbv[4] = {bb.x, bb.y, bb.z, bb.w};
        #pragma unroll
        for (int pf = 0; pf < 2; pf++) {
            int p = p0 + ph + pf * 16 + lo4;
            unsigned short b4[4];
            #pragma unroll
            for (int r = 0; r < 4; r++) b4[r] = f2bf(acc[of][pf][r] + bbv[r]);
            if (ob < 512) {              // wave-uniform branch (64-wide o-ranges)
                int gg = ob >> 7, rr = ob & 127;
                int hh = (rr & 63) >> 3, j0 = rr & 7;
                unsigned short* dst = (rr >= 64) ? kP : qP;
                *(ushort4*)&dst[((((size_t)(bB * 4 + gg)) * 8 + hh) * 1024 + (p & 1023)) * 32
                                + (p >> 10) * 8 + j0] = *(ushort4*)b4;
            } else {
                *(ushort4*)&vC[((size_t)(bB * 4096 + p)) * 256 + (ob - 512)] = *(ushort4*)b4;
                #pragma unroll
                for (int r = 0; r < 4; r++)
                    vT[((size_t)(bB * 256 + ob - 512 + r)) * 4096 + p] = b4[r];
            }
        }
    }
}

// MFMA area-attention (R8 form — best measured): barrier-free, packed Q/K,
// per-wave DOUBLE-BUFFERED P LDS (XOR-swizzled), spl=2, exp2f builtin.
__global__ __launch_bounds__(256) void attn_kernel(
    const unsigned short* __restrict__ qP, const unsigned short* __restrict__ kP,
    const unsigned short* __restrict__ vT,
    unsigned short* __restrict__ Opart, float* __restrict__ Lpart)
{
    __shared__ unsigned short Pq[4][2][32][64];   // [wave][buf][q][m], rows 128B, XOR-swizzled
    const int tid = threadIdx.x;
    const int w = tid >> 6, lane = tid & 63;
    const int lo4 = lane & 15, quad = lane >> 4;
    const int swz = (lo4 & 7) << 4;               // byte-XOR within 128B row
    const int n0 = blockIdx.z * 128;
    const int h = blockIdx.y;
    const int z = blockIdx.x;                     // 16 = ba(0..7)<<1 | spl
    const int ba = z >> 1, spl = z & 1;
    const int bB = ba >> 2, g = ba & 3;
    const int mbase = spl * 512;

    const unsigned short* qb = qP + (((size_t)(bB * 4) + g) * 8 + h) * 32768;
    const unsigned short* kb = kP + (((size_t)(bB * 4) + g) * 8 + h) * 32768;

    s8v qf[2];
    #pragma unroll
    for (int qc = 0; qc < 2; qc++)
        qf[qc] = *(const s8v*)(qb + (size_t)(n0 + w * 32 + qc * 16 + lo4) * 32 + quad * 8);
    const int dd0 = lo4, dd1 = 16 + lo4;
    const unsigned short* vb0 = vT + ((size_t)(bB * 256 + g * 64 + h * 8 + (dd0 & 7))) * 4096 + (dd0 >> 3) * 1024 + mbase + quad * 8;
    const unsigned short* vb1 = vT + ((size_t)(bB * 256 + g * 64 + h * 8 + (dd1 & 7))) * 4096 + (dd1 >> 3) * 1024 + mbase + quad * 8;

    f4v oacc[2][2], Lacc[2];
    #pragma unroll
    for (int i = 0; i < 2; i++) {
        Lacc[i] = (f4v){0.f, 0.f, 0.f, 0.f};
        #pragma unroll
        for (int j = 0; j < 2; j++)
            oacc[i][j] = (f4v){0.f, 0.f, 0.f, 0.f};
    }
    s8v ones;
    #pragma unroll
    for (int j = 0; j < 8; j++) ones[j] = (short)0x3F80;   // bf16 1.0

    s8v kf[4], vCur[2][2];
    #pragma unroll
    for (int mf = 0; mf < 4; mf++)
        kf[mf] = *(const s8v*)(kb + (size_t)(mbase + mf * 16 + lo4) * 32 + quad * 8);

    #pragma unroll
    for (int sc = 0; sc < 8; sc++) {
        // V for chunk sc (consumed by PV(sc) next iteration / epilogue)
        s8v vNew[2][2];
        #pragma unroll
        for (int mc = 0; mc < 2; mc++) {
            vNew[mc][0] = *(const s8v*)(vb0 + sc * 64 + mc * 32);
            vNew[mc][1] = *(const s8v*)(vb1 + sc * 64 + mc * 32);
        }
        // K for chunk sc+1
        s8v kfn[4];
        if (sc < 7) {
            #pragma unroll
            for (int mf = 0; mf < 4; mf++)
                kfn[mf] = *(const s8v*)(kb + (size_t)(mbase + (sc + 1) * 64 + mf * 16 + lo4) * 32 + quad * 8);
        }
        // QK(sc)
        f4v sT[4][2];
        __builtin_amdgcn_s_setprio(1);
        #pragma unroll
        for (int mf = 0; mf < 4; mf++)
            #pragma unroll
            for (int qc = 0; qc < 2; qc++)
                sT[mf][qc] = __builtin_amdgcn_mfma_f32_16x16x32_bf16(kf[mf], qf[qc], (f4v){0.f, 0.f, 0.f, 0.f}, 0, 0, 0);
        __builtin_amdgcn_s_setprio(0);
        // exp(sc) + write P(sc) into buf sc&1
        #pragma unroll
        for (int qc = 0; qc < 2; qc++) {
            char* prow = (char*)&Pq[w][sc & 1][qc * 16 + lo4][0];
            #pragma unroll
            for (int mf = 0; mf < 4; mf++) {
                float p0v = __builtin_amdgcn_exp2f(sT[mf][qc][0]);
                float p1v = __builtin_amdgcn_exp2f(sT[mf][qc][1]);
                float p2v = __builtin_amdgcn_exp2f(sT[mf][qc][2]);
                float p3v = __builtin_amdgcn_exp2f(sT[mf][qc][3]);
                uint2 pk;
                pk.x = trunc2(p0v, p1v);
                pk.y = trunc2(p2v, p3v);
                *(uint2*)(prow + ((mf * 32 + quad * 8) ^ swz)) = pk;
            }
        }
        // PV(sc-1) from the other buffer, V loaded last iteration
        if (sc > 0) {
            #pragma unroll
            for (int mc = 0; mc < 2; mc++) {
                s8v pfr[2];
                #pragma unroll
                for (int qc = 0; qc < 2; qc++)
                    pfr[qc] = *(const s8v*)((const char*)&Pq[w][(sc - 1) & 1][qc * 16 + lo4][0] + ((mc * 64 + quad * 16) ^ swz));
                __builtin_amdgcn_s_setprio(1);
                #pragma unroll
                for (int df = 0; df < 2; df++)
                    #pragma unroll
                    for (int qc = 0; qc < 2; qc++)
                        oacc[df][qc] = __builtin_amdgcn_mfma_f32_16x16x32_bf16(vCur[mc][df], pfr[qc], oacc[df][qc], 0, 0, 0);
                #pragma unroll
                for (int qc = 0; qc < 2; qc++)
                    Lacc[qc] = __builtin_amdgcn_mfma_f32_16x16x32_bf16(ones, pfr[qc], Lacc[qc], 0, 0, 0);
                __builtin_amdgcn_s_setprio(0);
            }
        }
        // rotate
        if (sc < 7) {
            #pragma unroll
            for (int mf = 0; mf < 4; mf++) kf[mf] = kfn[mf];
        }
        #pragma unroll
        for (int mc = 0; mc < 2; mc++) {
            vCur[mc][0] = vNew[mc][0];
            vCur[mc][1] = vNew[mc][1];
        }
    }
    // epilogue: PV(7) from buf 1
    #pragma unroll
    for (int mc = 0; mc < 2; mc++) {
        s8v pfr[2];
        #pragma unroll
        for (int qc = 0; qc < 2; qc++)
            pfr[qc] = *(const s8v*)((const char*)&Pq[w][1][qc * 16 + lo4][0] + ((mc * 64 + quad * 16) ^ swz));
        __builtin_amdgcn_s_setprio(1);
        #pragma unroll
        for (int df = 0; df < 2; df++)
            #pragma unroll
            for (int qc = 0; qc < 2; qc++)
                oacc[df][qc] = __builtin_amdgcn_mfma_f32_16x16x32_bf16(vCur[mc][df], pfr[qc], oacc[df][qc], 0, 0, 0);
        #pragma unroll
        for (int qc = 0; qc < 2; qc++)
            Lacc[qc] = __builtin_amdgcn_mfma_f32_16x16x32_bf16(ones, pfr[qc], Lacc[qc], 0, 0, 0);
        __builtin_amdgcn_s_setprio(0);
    }
    if (quad == 0) {
        size_t lb = (((size_t)(spl * 2 + bB) * 4 + g) * 8 + h) * 1024 + n0 + w * 32;
        Lpart[lb + lo4] = Lacc[0][0];
        Lpart[lb + 16 + lo4] = Lacc[1][0];
    }
    #pragma unroll
    for (int qc = 0; qc < 2; qc++)
        #pragma unroll
        for (int df = 0; df < 2; df++) {
            int pb = df * 2 + (quad >> 1);
            uint2 ov;
            ov.x = trunc2(oacc[df][qc][0], oacc[df][qc][1]);
            ov.y = trunc2(oacc[df][qc][2], oacc[df][qc][3]);
            *(uint2*)(Opart + ((size_t)(spl * 2 + bB) * 4096 + pb * 1024 + n0 + w * 32 + qc * 16 + lo4) * 256
                      + g * 64 + h * 8 + (quad & 1) * 4) = ov;
        }
}

// Fused combine+pe+proj+m1+m2 (R17 form, best verified): stage 3 K=320 (mh cols
// 320-383 exactly zero: Wm1 pad rows + bpad zero -> silu(0)=0, Wm2 pad cols zero).
__global__ __launch_bounds__(512) void mlp3_kernel(
    const unsigned short* __restrict__ Opart, const float* __restrict__ Lpart,
    const unsigned short* __restrict__ vC, const float* __restrict__ wpeT,
    const float* __restrict__ spe, const float* __restrict__ bpe,
    const float* __restrict__ x,
    const unsigned short* __restrict__ Wp, const float* __restrict__ bp,
    const unsigned short* __restrict__ Wm1, const float* __restrict__ bm1p,
    const unsigned short* __restrict__ Wm2, const float* __restrict__ bm2,
    float* __restrict__ out)
{
    __shared__ unsigned short bufA[16][392];  // [p][c]: attpe(256) then mh(384)
    __shared__ unsigned short bufX[16][264];  // [p][o]: x1 bf16
    const int tid = threadIdx.x, lane = tid & 63, wv = tid >> 6;   // wv 0..7
    const int lo4 = lane & 15, quad = lane >> 4;
    const int p0 = blockIdx.x * 16, bB = blockIdx.y;

    {   // fused attpe: combine Opart/Lpart + depthwise pe -> bufA [16p][256c]
        int row = tid >> 5, cg = (tid & 31) * 8;
        int p = p0 + row;
        int g = cg >> 6, h = (cg >> 3) & 7;
        int na = p & 1023;
        float L = 0.f;
        float o[8] = {};
        #pragma unroll
        for (int spl = 0; spl < 2; spl++) {
            L += Lpart[(((size_t)(spl * 2 + bB) * 4 + g) * 8 + h) * 1024 + na];
            uint4 v = *(const uint4*)(Opart + ((size_t)(spl * 2 + bB) * 4096 + p) * 256 + cg);
            unsigned short tmp[8]; *(uint4*)tmp = v;
            #pragma unroll
            for (int j = 0; j < 8; j++) o[j] += bf2f(tmp[j]);
        }
        float inv = 1.f / L;
        int hh = p >> 6, ww = p & 63;
        float pe[8] = {};
        for (int di = -1; di <= 1; di++) {
            int h2 = hh + di;
            if (h2 < 0 || h2 > 63) continue;
            for (int dj = -1; dj <= 1; dj++) {
                int w2 = ww + dj;
                if (w2 < 0 || w2 > 63) continue;
                uint4 vv = *(const uint4*)(vC + ((size_t)(bB * 4096 + h2 * 64 + w2)) * 256 + cg);
                unsigned short tmp[8]; *(uint4*)tmp = vv;
                int k = (di + 1) * 3 + (dj + 1);
                float4 wa = *(const float4*)&wpeT[k * 256 + cg];
                float4 wb = *(const float4*)&wpeT[k * 256 + cg + 4];
                float ww8[8] = {wa.x, wa.y, wa.z, wa.w, wb.x, wb.y, wb.z, wb.w};
                #pragma unroll
                for (int j = 0; j < 8; j++)
                    pe[j] = fmaf(bf2f(tmp[j]), ww8[j], pe[j]);
            }
        }
        float4 sa = *(const float4*)&spe[cg];
        float4 sb = *(const float4*)&spe[cg + 4];
        float4 b0 = *(const float4*)&bpe[cg];
        float4 b1 = *(const float4*)&bpe[cg + 4];
        float sv8[8] = {sa.x, sa.y, sa.z, sa.w, sb.x, sb.y, sb.z, sb.w};
        float bv8[8] = {b0.x, b0.y, b0.z, b0.w, b1.x, b1.y, b1.z, b1.w};
        unsigned short ob8[8];
        #pragma unroll
        for (int j = 0; j < 8; j++)
            ob8[j] = f2bf(o[j] * inv + pe[j] * sv8[j] + bv8[j]);
        *(uint4*)&bufA[row][cg] = *(uint4*)ob8;
    }
    __syncthreads();

    // ---- stage 1: x1 = x + proj(attpe); wave o-range wv*32..+31, K=256
    {
        f4v acc[2] = {(f4v){0.f, 0.f, 0.f, 0.f}, (f4v){0.f, 0.f, 0.f, 0.f}};
        #pragma unroll
        for (int kk = 0; kk < 8; kk++) {
            s8v bx = *(const s8v*)&bufA[lo4][kk * 32 + quad * 8];
            #pragma unroll
            for (int of = 0; of < 2; of++) {
                s8v af = *(const s8v*)(Wp + (size_t)(wv * 32 + of * 16 + lo4) * 256 + kk * 32 + quad * 8);
                acc[of] = __builtin_amdgcn_mfma_f32_16x16x32_bf16(af, bx, acc[of], 0, 0, 0);
            }
        }
        #pragma unroll
        for (int of = 0; of < 2; of++) {
            int ob = wv * 32 + of * 16 + quad * 4;
            float4 bb = *(const float4*)&bp[ob];
            float bbv[4] = {bb.x, bb.y, bb.z, bb.w};
            int p = p0 + lo4;
            unsigned short b4[4];
            #pragma unroll
            for (int r = 0; r < 4; r++) {
                float y = acc[of][r] + bbv[r] + x[((size_t)(bB * 256 + ob + r)) * 4096 + p];
                b4[r] = f2bf(y);
            }
            *(ushort4*)&bufX[lo4][ob] = *(ushort4*)b4;
        }
    }
    __syncthreads();

    // ---- stage 2: mh = silu(m1(x1)); wave o-range wv*48..+47, K=256
    {
        f4v acc[3] = {(f4v){0.f, 0.f, 0.f, 0.f}, (f4v){0.f, 0.f, 0.f, 0.f}, (f4v){0.f, 0.f, 0.f, 0.f}};
        #pragma unroll
        for (int kk = 0; kk < 8; kk++) {
            s8v bx = *(const s8v*)&bufX[lo4][kk * 32 + quad * 8];
            #pragma unroll
            for (int of = 0; of < 3; of++) {
                s8v af = *(const s8v*)(Wm1 + (size_t)(wv * 48 + of * 16 + lo4) * 256 + kk * 32 + quad * 8);
                acc[of] = __builtin_amdgcn_mfma_f32_16x16x32_bf16(af, bx, acc[of], 0, 0, 0);
            }
        }
        #pragma unroll
        for (int of = 0; of < 3; of++) {
            int ob = wv * 48 + of * 16 + quad * 4;
            float4 bb = *(const float4*)&bm1p[ob];
            float bbv[4] = {bb.x, bb.y, bb.z, bb.w};
            unsigned short b4[4];
            #pragma unroll
            for (int r = 0; r < 4; r++) {
                float y = acc[of][r] + bbv[r];
                y = y / (1.f + __expf(-y));
                b4[r] = f2bf(y);
            }
            *(ushort4*)&bufA[lo4][ob] = *(ushort4*)b4;
        }
    }
    __syncthreads();

    // ---- stage 3: out = x1 + m2(mh); wave o-range wv*32..+31, K=320 (cols 320-383
    // of Wm2 and mh are exactly zero — dead K-tiles skipped), transposed stores
    {
        f4v acc[2] = {(f4v){0.f, 0.f, 0.f, 0.f}, (f4v){0.f, 0.f, 0.f, 0.f}};
        #pragma unroll
        for (int kk = 0; kk < 10; kk++) {
            s8v bx = *(const s8v*)&bufA[lo4][kk * 32 + quad * 8];
            #pragma unroll
            for (int of = 0; of < 2; of++) {
                s8v af = *(const s8v*)(Wm2 + (size_t)(wv * 32 + of * 16 + lo4) * 384 + kk * 32 + quad * 8);
                acc[of] = __builtin_amdgcn_mfma_f32_16x16x32_bf16(af, bx, acc[of], 0, 0, 0);
            }
        }
        #pragma unroll
        for (int of = 0; of < 2; of++) {
            int ob = wv * 32 + of * 16 + quad * 4;
            float4 bb = *(const float4*)&bm2[ob];
            float bbv[4] = {bb.x, bb.y, bb.z, bb.w};
            ushort4 x1v = *(const ushort4*)&bufX[lo4][ob];
            unsigned short x1a[4]; *(ushort4*)x1a = x1v;
            #pragma unroll
            for (int r = 0; r < 4; r++) {
                float y = acc[of][r] + bbv[r] + bf2f(x1a[r]);
                out[((size_t)(bB * 256 + ob + r)) * 4096 + p0 + lo4] = y;
            }
        }
    }
}

extern "C" void kernel_launch(void* const* d_in, const int* in_sizes, int n_in,
                              void* d_out, int out_size, void* d_ws, size_t ws_size,
                              hipStream_t stream)
{
    const float* x      = (const float*)d_in[0];
    const float* w_qk   = (const float*)d_in[1];
    const float* s_qk   = (const float*)d_in[2];
    const float* b_qk   = (const float*)d_in[3];
    const float* w_v    = (const float*)d_in[4];
    const float* s_v    = (const float*)d_in[5];
    const float* b_v    = (const float*)d_in[6];
    const float* w_pe   = (const float*)d_in[7];
    const float* s_pe   = (const float*)d_in[8];
    const float* b_pe   = (const float*)d_in[9];
    const float* w_proj = (const float*)d_in[10];
    const float* s_proj = (const float*)d_in[11];
    const float* b_proj = (const float*)d_in[12];
    const float* w_m1   = (const float*)d_in[13];
    const float* s_m1   = (const float*)d_in[14];
    const float* b_m1   = (const float*)d_in[15];
    const float* w_m2   = (const float*)d_in[16];
    const float* s_m2   = (const float*)d_in[17];
    const float* b_m2   = (const float*)d_in[18];
    float* out = (float*)d_out;

    const size_t NA = (size_t)2 * 4096 * 256;     // 2,097,152
    unsigned short* vC   = (unsigned short*)d_ws; // bf16 [b][p][256] (V only)
    unsigned short* qP   = vC + NA;               // bf16 packed [b][g][h][1024][4][8]
    unsigned short* kP   = qP + NA;               // bf16 packed [b][g][h][1024][4][8]
    unsigned short* Opart = kP + NA;              // bf16 [2][b][p][256]
    float* Lpart = (float*)(Opart + 2 * NA);      // fp32 [2][b][4][8][1024]
    unsigned short* vT   = (unsigned short*)(Lpart + 131072);  // bf16 [b][256][4096]
    unsigned short* Wqkv = vT + NA;
    unsigned short* Wp   = Wqkv + 196608;
    unsigned short* Wm1  = Wp + 65536;
    unsigned short* Wm2  = Wm1 + 98304;
    float* bpad = (float*)(Wm2 + 98304);
    float* bqv  = bpad + 384;
    float* wpeT = bqv + 768;                       // fp32 [9][256]

    dim3 blk(256);
    wconv_kernel<<<dim3(1806), blk, 0, stream>>>(
        w_qk, s_qk, b_qk, w_v, s_v, b_v, w_proj, s_proj,
        w_m1, s_m1, b_m1, w_m2, s_m2, w_pe,
        Wqkv, Wp, Wm1, Wm2, bpad, bqv, wpeT);

    mmqkv_kernel<<<dim3(64, 6, 2), blk, 0, stream>>>(x, Wqkv, bqv, qP, kP, vC, vT);

    attn_kernel<<<dim3(16, 8, 8), blk, 0, stream>>>(qP, kP, vT, Opart, Lpart);

    // fused combine + pe + proj + m1 + m2 (+ both residuals), out transposed fp32
    mlp3_kernel<<<dim3(256, 2), dim3(512), 0, stream>>>(
        Opart, Lpart, vC, wpeT, s_pe, b_pe,
        x, Wp, b_proj, Wm1, bpad, Wm2, b_m2, out);
}